// Round 3
// baseline (725.535 us; speedup 1.0000x reference)
//
#include <hip/hip_runtime.h>
#include <stdint.h>

// ---------- types ----------
typedef int i32x4 __attribute__((ext_vector_type(4)));

#define PIDX(e) ((e) + ((e) >> 5))   // +1 dword pad per 32 to break LDS bank conflicts

// ---------- wave/block reductions (256 threads = 4 waves) ----------
__device__ __forceinline__ float wred_sum(float v) {
#pragma unroll
    for (int o = 32; o > 0; o >>= 1) v += __shfl_down(v, o, 64);
    return v;
}
__device__ __forceinline__ float wred_max(float v) {
#pragma unroll
    for (int o = 32; o > 0; o >>= 1) v = fmaxf(v, __shfl_down(v, o, 64));
    return v;
}
__device__ __forceinline__ float bred_sum(float v, float* sb, int tid) {
    v = wred_sum(v);
    __syncthreads();
    if ((tid & 63) == 0) sb[tid >> 6] = v;
    __syncthreads();
    return sb[0] + sb[1] + sb[2] + sb[3];
}
__device__ __forceinline__ float bred_max(float v, float* sb, int tid) {
    v = wred_max(v);
    __syncthreads();
    if ((tid & 63) == 0) sb[tid >> 6] = v;
    __syncthreads();
    return fmaxf(fmaxf(sb[0], sb[1]), fmaxf(sb[2], sb[3]));
}

__device__ __forceinline__ int pack4(int a, int b, int c, int d) {
    return (a & 0xff) | ((b & 0xff) << 8) | ((c & 0xff) << 16) | ((d & 0xff) << 24);
}

// ---------- 16-point in-register FWHT ----------
__device__ __forceinline__ void fwht16(float v[16]) {
#pragma unroll
    for (int h = 1; h < 16; h <<= 1) {
#pragma unroll
        for (int i = 0; i < 16; ++i) {
            if ((i & h) == 0) {
                float a = v[i], b = v[i + h];
                v[i] = a + b;
                v[i + h] = a - b;
            }
        }
    }
}

// FWHT of 4096 floats living in padded LDS f[PIDX(e)], 256 threads.
__device__ void fwht4096(float* f, int t) {
    __syncthreads();
    float v[16];
    {   // bits 0-3
        int base = t << 4;
#pragma unroll
        for (int i = 0; i < 16; ++i) v[i] = f[PIDX(base + i)];
        fwht16(v);
#pragma unroll
        for (int i = 0; i < 16; ++i) f[PIDX(base + i)] = v[i];
    }
    __syncthreads();
    {   // bits 4-7
        int base = ((t >> 4) << 8) | (t & 15);
#pragma unroll
        for (int i = 0; i < 16; ++i) v[i] = f[PIDX(base + (i << 4))];
        fwht16(v);
#pragma unroll
        for (int i = 0; i < 16; ++i) f[PIDX(base + (i << 4))] = v[i];
    }
    __syncthreads();
    {   // bits 8-11
        int base = t;
#pragma unroll
        for (int i = 0; i < 16; ++i) v[i] = f[PIDX(base + (i << 8))];
        fwht16(v);
#pragma unroll
        for (int i = 0; i < 16; ++i) f[PIDX(base + (i << 8))] = v[i];
    }
    __syncthreads();
}

// ---------- K1a: partial sums of |w| ----------
__global__ __launch_bounds__(256) void k_wabs(const float* __restrict__ w,
                                              float* __restrict__ partials) {
    __shared__ float sb[4];
    const int t = threadIdx.x;
    const int b = blockIdx.x;
    float acc = 0.0f;
#pragma unroll
    for (int i = 0; i < 8; ++i) {
        float4 f = *(const float4*)(w + (size_t)(b * 2048 + i * 256 + t) * 4);
        acc += fabsf(f.x) + fabsf(f.y) + fabsf(f.z) + fabsf(f.w);
    }
    float tot = bred_sum(acc, sb, t);
    if (t == 0) partials[b] = tot;
}

// ---------- K1a2: final scale = mean|w| ----------
__global__ __launch_bounds__(256) void k_wscale(const float* __restrict__ partials,
                                                float* __restrict__ sfinal) {
    __shared__ float sb[4];
    const int t = threadIdx.x;
    float a = 0.0f;
#pragma unroll
    for (int i = 0; i < 8; ++i) a += partials[t + i * 256];
    float tot = bred_sum(a, sb, t);
    if (t == 0) sfinal[0] = tot * (1.0f / 16777216.0f);
}

// ---------- K1b: ternary quantize weight row, FWHT, split into hi/lo i8 ----------
__global__ __launch_bounds__(256) void k_wprep(const float* __restrict__ w,
                                               const float* __restrict__ sfinal,
                                               int8_t* __restrict__ hi,
                                               int8_t* __restrict__ lo) {
    __shared__ float f[4224];
    const int t = threadIdx.x;
    const int o = blockIdx.x;
    const float thr = 0.5f * sfinal[0];
    const float* wr = w + (size_t)o * 4096;
#pragma unroll
    for (int j = 0; j < 4; ++j) {
        float4 g = *(const float4*)(wr + j * 1024 + t * 4);
        int e = j * 1024 + t * 4;
        f[PIDX(e + 0)] = (g.x > thr) ? 1.0f : ((g.x < -thr) ? -1.0f : 0.0f);
        f[PIDX(e + 1)] = (g.y > thr) ? 1.0f : ((g.y < -thr) ? -1.0f : 0.0f);
        f[PIDX(e + 2)] = (g.z > thr) ? 1.0f : ((g.z < -thr) ? -1.0f : 0.0f);
        f[PIDX(e + 3)] = (g.w > thr) ? 1.0f : ((g.w < -thr) ? -1.0f : 0.0f);
    }
    fwht4096(f, t);
    int* hi32 = (int*)hi;
    int* lo32 = (int*)lo;
#pragma unroll
    for (int j = 0; j < 4; ++j) {
        int e = j * 1024 + t * 4;
        int l4[4], h4[4];
#pragma unroll
        for (int q = 0; q < 4; ++q) {
            int v = __float2int_rn(f[PIDX(e + q)]);       // exact integer in [-4096,4096]
            int lv = ((v + 128) & 255) - 128;             // [-128,127]
            int hv = (v - lv) >> 8;                       // [-16,16]
            l4[q] = lv; h4[q] = hv;
        }
        lo32[(size_t)o * 1024 + j * 256 + t] = pack4(l4[0], l4[1], l4[2], l4[3]);
        hi32[(size_t)o * 1024 + j * 256 + t] = pack4(h4[0], h4[1], h4[2], h4[3]);
    }
}

// ---------- K2: fused LayerNorm + absmax + int4 quantize -> i8 ----------
__global__ __launch_bounds__(256) void k_lnq(const float* __restrict__ x,
                                             const float* __restrict__ gamma,
                                             const float* __restrict__ beta,
                                             int8_t* __restrict__ xq) {
    __shared__ float sb[4];
    const int t = threadIdx.x;
    const size_t row = blockIdx.x;
    const float* xr = x + row * 4096;
    float v[16];
#pragma unroll
    for (int j = 0; j < 4; ++j) {
        float4 g = *(const float4*)(xr + j * 1024 + t * 4);
        v[j * 4 + 0] = g.x; v[j * 4 + 1] = g.y; v[j * 4 + 2] = g.z; v[j * 4 + 3] = g.w;
    }
    float s = 0.0f;
#pragma unroll
    for (int i = 0; i < 16; ++i) s += v[i];
    const float mu = bred_sum(s, sb, t) * (1.0f / 4096.0f);
    float sq = 0.0f;
#pragma unroll
    for (int i = 0; i < 16; ++i) { float d = v[i] - mu; sq += d * d; }
    const float var = bred_sum(sq, sb, t) * (1.0f / 4096.0f);
    const float rstd = rsqrtf(var + 1e-5f);
#pragma unroll
    for (int j = 0; j < 4; ++j) {
        float4 g = *(const float4*)(gamma + j * 1024 + t * 4);
        float4 b = *(const float4*)(beta + j * 1024 + t * 4);
        v[j * 4 + 0] = (v[j * 4 + 0] - mu) * rstd * g.x + b.x;
        v[j * 4 + 1] = (v[j * 4 + 1] - mu) * rstd * g.y + b.y;
        v[j * 4 + 2] = (v[j * 4 + 2] - mu) * rstd * g.z + b.z;
        v[j * 4 + 3] = (v[j * 4 + 3] - mu) * rstd * g.w + b.w;
    }
    float am = 0.0f;
#pragma unroll
    for (int i = 0; i < 16; ++i) am = fmaxf(am, fabsf(v[i]));
    am = bred_max(am, sb, t);
    const float scale = fminf(fmaxf(am, 1e-6f), 1e6f);
    const float sf = fminf(fmaxf(7.0f / scale, 1e-6f), 1e6f);
    int* xq32 = (int*)xq;
#pragma unroll
    for (int j = 0; j < 4; ++j) {
        int q4[4];
#pragma unroll
        for (int q = 0; q < 4; ++q) {
            float qq = rintf(v[j * 4 + q] * sf);
            qq = fminf(fmaxf(qq, -7.0f), 7.0f);
            q4[q] = (int)qq;
        }
        xq32[row * 1024 + j * 256 + t] = pack4(q4[0], q4[1], q4[2], q4[3]);
    }
}

// ---------- async global -> LDS, 16B per lane ----------
__device__ __forceinline__ void gl_lds16(const void* g, void* l) {
    __builtin_amdgcn_global_load_lds(
        (const __attribute__((address_space(1))) void*)g,
        (__attribute__((address_space(3))) void*)l, 16, 0, 0);
}

// ---------- K3: pipelined dual i8 GEMM ----------
// out[r,o] = s * sum_d xq[r,d] * (256*hi[o,d] + lo[o,d])      (bit-exact i32)
// BM=256, BN=128, BK=64, 512 threads = 8 waves (4M x 2N), per-wave 64x64 out.
// Double-buffered LDS (64 KiB), burst prefetch at phase 0, vmcnt(0) only at
// K-tile end (issue->wait distance = 2 phases), raw s_barrier (no vmcnt drain),
// setprio around MFMA clusters. LDS chunk swizzle as before (measured 0 confl).
__global__ __launch_bounds__(512, 2) void k_gemm(const int8_t* __restrict__ xq,
                                                 const int8_t* __restrict__ hi,
                                                 const int8_t* __restrict__ lo,
                                                 const float* __restrict__ sfinal,
                                                 float* __restrict__ out) {
    __shared__ __align__(16) int8_t sA[2][16384];   // [buf][256 rows x 64]
    __shared__ __align__(16) int8_t sH[2][8192];    // [buf][128 rows x 64]
    __shared__ __align__(16) int8_t sL[2][8192];
    const int tid = threadIdx.x;
    const int lane = tid & 63, wid = tid >> 6;
    const int wm = wid >> 1, wn = wid & 1;          // 4M x 2N waves
    // XCD-aware bijective swizzle: 1024 wgs = 8 XCD chunks of 128
    const int bid = blockIdx.x;
    const int wg = (bid & 7) * 128 + (bid >> 3);
    const int bm = wg & 31, bn = wg >> 5;           // 32 x 32 blocks
    const int row0 = bm * 256, col0 = bn * 128;

    // ---- staging source (chunk-swizzled global addr, lane-linear LDS dest) ----
    const int srow = tid >> 2;                       // 0..127
    const int scol = (((tid & 3) ^ ((srow >> 1) & 3))) * 16;
    const int8_t* gA0 = xq + (size_t)(row0 + srow) * 4096 + scol;
    const int8_t* gA1 = gA0 + (size_t)128 * 4096;    // phi(row+128)==phi(row)
    const int8_t* gH0 = hi + (size_t)(col0 + srow) * 4096 + scol;
    const int8_t* gL0 = lo + (size_t)(col0 + srow) * 4096 + scol;
    int8_t* dA = (int8_t*)sA + tid * 16;             // + buf*16384 (+8192 second half)
    int8_t* dH = (int8_t*)sH + tid * 16;             // + buf*8192
    int8_t* dL = (int8_t*)sL + tid * 16;

#define STAGE(buf_, kt_) do { const int o_ = (kt_) * 64;            \
        gl_lds16(gA0 + o_, dA + (buf_) * 16384);                    \
        gl_lds16(gA1 + o_, dA + (buf_) * 16384 + 8192);             \
        gl_lds16(gH0 + o_, dH + (buf_) * 8192);                     \
        gl_lds16(gL0 + o_, dL + (buf_) * 8192); } while (0)

    // ---- fragment read offsets (phi invariant under row += 16/64) ----
    const int frow = lane & 15;
    const int kg = lane >> 4;
    const int swz = ((kg ^ ((frow >> 1) & 3))) * 16;
    const int aoff = (wm * 64 + frow) * 64 + swz;    // + m*1024
    const int boff = (wn * 64 + frow) * 64 + swz;    // + n*1024

    i32x4 accL[4][4] = {};
    i32x4 accH[4][4] = {};

    // prologue: stage tile 0
    STAGE(0, 0);
    asm volatile("s_waitcnt vmcnt(0)" ::: "memory");
    asm volatile("s_barrier" ::: "memory");

    for (int kt = 0; kt < 64; ++kt) {
        const int cur = kt & 1;
        const int8_t* A = sA[cur];
        const int8_t* H = sH[cur];
        const int8_t* L = sL[cur];

        // ---- phase 0: prefetch next tile, read A(all m) + B(n=0,1), 16 MFMA ----
        if (kt < 63) STAGE(cur ^ 1, kt + 1);
        i32x4 a0 = *(const i32x4*)(A + aoff);
        i32x4 a1 = *(const i32x4*)(A + aoff + 1024);
        i32x4 a2 = *(const i32x4*)(A + aoff + 2048);
        i32x4 a3 = *(const i32x4*)(A + aoff + 3072);
        i32x4 h0 = *(const i32x4*)(H + boff);
        i32x4 h1 = *(const i32x4*)(H + boff + 1024);
        i32x4 l0 = *(const i32x4*)(L + boff);
        i32x4 l1 = *(const i32x4*)(L + boff + 1024);
        asm volatile("s_barrier" ::: "memory");
        asm volatile("s_waitcnt lgkmcnt(0)" ::: "memory");
        __builtin_amdgcn_s_setprio(1);
        accL[0][0] = __builtin_amdgcn_mfma_i32_16x16x64_i8(a0, l0, accL[0][0], 0, 0, 0);
        accH[0][0] = __builtin_amdgcn_mfma_i32_16x16x64_i8(a0, h0, accH[0][0], 0, 0, 0);
        accL[0][1] = __builtin_amdgcn_mfma_i32_16x16x64_i8(a0, l1, accL[0][1], 0, 0, 0);
        accH[0][1] = __builtin_amdgcn_mfma_i32_16x16x64_i8(a0, h1, accH[0][1], 0, 0, 0);
        accL[1][0] = __builtin_amdgcn_mfma_i32_16x16x64_i8(a1, l0, accL[1][0], 0, 0, 0);
        accH[1][0] = __builtin_amdgcn_mfma_i32_16x16x64_i8(a1, h0, accH[1][0], 0, 0, 0);
        accL[1][1] = __builtin_amdgcn_mfma_i32_16x16x64_i8(a1, l1, accL[1][1], 0, 0, 0);
        accH[1][1] = __builtin_amdgcn_mfma_i32_16x16x64_i8(a1, h1, accH[1][1], 0, 0, 0);
        accL[2][0] = __builtin_amdgcn_mfma_i32_16x16x64_i8(a2, l0, accL[2][0], 0, 0, 0);
        accH[2][0] = __builtin_amdgcn_mfma_i32_16x16x64_i8(a2, h0, accH[2][0], 0, 0, 0);
        accL[2][1] = __builtin_amdgcn_mfma_i32_16x16x64_i8(a2, l1, accL[2][1], 0, 0, 0);
        accH[2][1] = __builtin_amdgcn_mfma_i32_16x16x64_i8(a2, h1, accH[2][1], 0, 0, 0);
        accL[3][0] = __builtin_amdgcn_mfma_i32_16x16x64_i8(a3, l0, accL[3][0], 0, 0, 0);
        accH[3][0] = __builtin_amdgcn_mfma_i32_16x16x64_i8(a3, h0, accH[3][0], 0, 0, 0);
        accL[3][1] = __builtin_amdgcn_mfma_i32_16x16x64_i8(a3, l1, accL[3][1], 0, 0, 0);
        accH[3][1] = __builtin_amdgcn_mfma_i32_16x16x64_i8(a3, h1, accH[3][1], 0, 0, 0);
        __builtin_amdgcn_s_setprio(0);
        asm volatile("s_barrier" ::: "memory");

        // ---- phase 1: read B(n=2,3), 16 MFMA, then wait prefetch ----
        i32x4 h2 = *(const i32x4*)(H + boff + 2048);
        i32x4 h3 = *(const i32x4*)(H + boff + 3072);
        i32x4 l2 = *(const i32x4*)(L + boff + 2048);
        i32x4 l3 = *(const i32x4*)(L + boff + 3072);
        asm volatile("s_barrier" ::: "memory");
        asm volatile("s_waitcnt lgkmcnt(0)" ::: "memory");
        __builtin_amdgcn_s_setprio(1);
        accL[0][2] = __builtin_amdgcn_mfma_i32_16x16x64_i8(a0, l2, accL[0][2], 0, 0, 0);
        accH[0][2] = __builtin_amdgcn_mfma_i32_16x16x64_i8(a0, h2, accH[0][2], 0, 0, 0);
        accL[0][3] = __builtin_amdgcn_mfma_i32_16x16x64_i8(a0, l3, accL[0][3], 0, 0, 0);
        accH[0][3] = __builtin_amdgcn_mfma_i32_16x16x64_i8(a0, h3, accH[0][3], 0, 0, 0);
        accL[1][2] = __builtin_amdgcn_mfma_i32_16x16x64_i8(a1, l2, accL[1][2], 0, 0, 0);
        accH[1][2] = __builtin_amdgcn_mfma_i32_16x16x64_i8(a1, h2, accH[1][2], 0, 0, 0);
        accL[1][3] = __builtin_amdgcn_mfma_i32_16x16x64_i8(a1, l3, accL[1][3], 0, 0, 0);
        accH[1][3] = __builtin_amdgcn_mfma_i32_16x16x64_i8(a1, h3, accH[1][3], 0, 0, 0);
        accL[2][2] = __builtin_amdgcn_mfma_i32_16x16x64_i8(a2, l2, accL[2][2], 0, 0, 0);
        accH[2][2] = __builtin_amdgcn_mfma_i32_16x16x64_i8(a2, h2, accH[2][2], 0, 0, 0);
        accL[2][3] = __builtin_amdgcn_mfma_i32_16x16x64_i8(a2, l3, accL[2][3], 0, 0, 0);
        accH[2][3] = __builtin_amdgcn_mfma_i32_16x16x64_i8(a2, h3, accH[2][3], 0, 0, 0);
        accL[3][2] = __builtin_amdgcn_mfma_i32_16x16x64_i8(a3, l2, accL[3][2], 0, 0, 0);
        accH[3][2] = __builtin_amdgcn_mfma_i32_16x16x64_i8(a3, h2, accH[3][2], 0, 0, 0);
        accL[3][3] = __builtin_amdgcn_mfma_i32_16x16x64_i8(a3, l3, accL[3][3], 0, 0, 0);
        accH[3][3] = __builtin_amdgcn_mfma_i32_16x16x64_i8(a3, h3, accH[3][3], 0, 0, 0);
        __builtin_amdgcn_s_setprio(0);
        asm volatile("s_waitcnt vmcnt(0)" ::: "memory");   // next tile staged
        asm volatile("s_barrier" ::: "memory");
    }
#undef STAGE

    const float s = sfinal[0];
    const int orow0 = row0 + wm * 64 + kg * 4;
    const int ocol0 = col0 + wn * 64 + frow;
#pragma unroll
    for (int m = 0; m < 4; ++m)
#pragma unroll
        for (int n = 0; n < 4; ++n)
#pragma unroll
            for (int r = 0; r < 4; ++r) {
                int val = accL[m][n][r] + (accH[m][n][r] << 8);   // exact i32
                out[(size_t)(orow0 + m * 16 + r) * 4096 + (ocol0 + n * 16)] = s * (float)val;
            }
}

// ---------- K4: in-place FWHT along output dim ----------
__global__ __launch_bounds__(256) void k_fwht_out(float* __restrict__ out) {
    __shared__ float f[4224];
    const int t = threadIdx.x;
    float* row = out + (size_t)blockIdx.x * 4096;
#pragma unroll
    for (int j = 0; j < 4; ++j) {
        float4 g = *(const float4*)(row + j * 1024 + t * 4);
        int e = j * 1024 + t * 4;
        f[PIDX(e + 0)] = g.x; f[PIDX(e + 1)] = g.y;
        f[PIDX(e + 2)] = g.z; f[PIDX(e + 3)] = g.w;
    }
    fwht4096(f, t);
#pragma unroll
    for (int j = 0; j < 4; ++j) {
        int e = j * 1024 + t * 4;
        float4 g;
        g.x = f[PIDX(e + 0)]; g.y = f[PIDX(e + 1)];
        g.z = f[PIDX(e + 2)]; g.w = f[PIDX(e + 3)];
        *(float4*)(row + e) = g;
    }
}

// ---------- launch ----------
extern "C" void kernel_launch(void* const* d_in, const int* in_sizes, int n_in,
                              void* d_out, int out_size, void* d_ws, size_t ws_size,
                              hipStream_t stream) {
    const float* x     = (const float*)d_in[0];
    const float* gamma = (const float*)d_in[1];
    const float* beta  = (const float*)d_in[2];
    const float* w     = (const float*)d_in[3];
    float* out = (float*)d_out;

    char* ws = (char*)d_ws;
    float* sfinal   = (float*)ws;                       // 4 B
    float* partials = (float*)(ws + 256);               // 2048 floats
    int8_t* xq  = (int8_t*)(ws + 16384);                // 33.5 MB
    int8_t* whi = (int8_t*)(ws + 16384 + 33554432);     // 16.7 MB
    int8_t* wlo = (int8_t*)(ws + 16384 + 33554432 + 16777216); // 16.7 MB

    k_wabs  <<<2048, 256, 0, stream>>>(w, partials);
    k_wscale<<<   1, 256, 0, stream>>>(partials, sfinal);
    k_wprep <<<4096, 256, 0, stream>>>(w, sfinal, whi, wlo);
    k_lnq   <<<8192, 256, 0, stream>>>(x, gamma, beta, xq);
    k_gemm  <<<1024, 512, 0, stream>>>(xq, whi, wlo, sfinal, out);
    k_fwht_out<<<8192, 256, 0, stream>>>(out);
}